// Round 14
// baseline (176.098 us; speedup 1.0000x reference)
//
#include <hip/hip_runtime.h>
#include <math.h>

#define EPSV 1.1920929e-07f

typedef __attribute__((ext_vector_type(8))) short short8;
typedef __attribute__((ext_vector_type(4))) float f32x4;

__device__ __forceinline__ float bf2f(unsigned short u) {
    union { unsigned int i; float f; } c; c.i = ((unsigned int)u) << 16; return c.f;
}
__device__ __forceinline__ unsigned short f2bf(float f) {
    union { float f; unsigned int i; } c; c.f = f;
    unsigned int r = c.i + 0x7FFFu + ((c.i >> 16) & 1u);   // RNE
    return (unsigned short)(r >> 16);
}
// pack two f32 -> two bf16 (round-half-up) in one u32: low=a, high=b
__device__ __forceinline__ unsigned int pack_bf16_ru(float a, float b) {
    union { float f; unsigned int i; } ca, cb; ca.f = a; cb.f = b;
    return __builtin_amdgcn_perm(cb.i + 0x8000u, ca.i + 0x8000u, 0x07060302u);
}
// async global -> LDS, 16 B per lane (dest = wave-uniform base + lane*16)
__device__ __forceinline__ void async_lds16(const unsigned short* g, unsigned short* l) {
    __builtin_amdgcn_global_load_lds(
        (const __attribute__((address_space(1))) unsigned int*)g,
        (__attribute__((address_space(3))) unsigned int*)l, 16, 0, 0);
}

// ======================================================================
// MERGED prep: fp32->bf16 cast of x | transpose+cast of both weights |
// packed cos/sin table cs[T][32] (float2; cos[d]=cos[d%32] by concat).
// ======================================================================
__global__ __launch_bounds__(256) void prep_cast_transpose(
    const float* __restrict__ x, unsigned short* __restrict__ xb, int nCast,
    const float* __restrict__ Wa, unsigned short* __restrict__ Wat,
    const float* __restrict__ Wp, unsigned short* __restrict__ Wpt,
    const float* __restrict__ cosp, const float* __restrict__ sinp,
    float2* __restrict__ cs, int castBlocks)
{
    __shared__ float tile[32][33];
    const int bxg = blockIdx.x;
    if (bxg < castBlocks) {
        const int i = (bxg * 256 + threadIdx.x) * 4;
        if (i >= nCast) return;
        const float4 v = *(const float4*)&x[i];
        ushort4 o;
        o.x = f2bf(v.x); o.y = f2bf(v.y); o.z = f2bf(v.z); o.w = f2bf(v.w);
        *(ushort4*)&xb[i] = o;
        return;
    }
    if (bxg >= castBlocks + 4096) {   // cs table part
        const int i = (bxg - castBlocks - 4096) * 256 + threadIdx.x;
        const int tp = i >> 5, dp = i & 31;
        cs[i] = make_float2(cosp[tp * 64 + dp], sinp[tp * 64 + dp]);
        return;
    }
    const int r0 = bxg - castBlocks;
    int bx = r0 & 127;                      // 0..127
    const int by = r0 >> 7;                 // 0..31
    const float* W; unsigned short* Wt; int N;
    if (bx < 96) { W = Wa; Wt = Wat; N = 3072; }
    else         { W = Wp; Wt = Wpt; N = 1024; bx -= 96; }
    const int n0 = bx * 32, k0 = by * 32;
    const int r = threadIdx.x >> 3, c4 = (threadIdx.x & 7) * 4;
    const float4 v = *(const float4*)&W[(size_t)(k0 + r) * N + n0 + c4];
    tile[r][c4 + 0] = v.x; tile[r][c4 + 1] = v.y;
    tile[r][c4 + 2] = v.z; tile[r][c4 + 3] = v.w;
    __syncthreads();
    ushort4 o;
    o.x = f2bf(tile[c4 + 0][r]); o.y = f2bf(tile[c4 + 1][r]);
    o.z = f2bf(tile[c4 + 2][r]); o.w = f2bf(tile[c4 + 3][r]);
    *(ushort4*)&Wt[(size_t)(n0 + r) * 1024 + k0 + c4] = o;
}

// ======================================================================
// FUSED qkv GEMM (N=3072) with fused RMSNorm+RoPE / V-transpose epilogue.
// R13 structure (1-phase BK=64, verified 48.8 us) + R14: chunk-XOR bank
// swizzle on A/B staging+reads. The [128][32] layout's frag read put 16
// lanes on 2 bank groups (8-way b128 conflict, ~264 cyc/step of the
// 2440-cyc step). Source chunk (lane&3)^(row&3), read chunk quad^(col&3)
// -- same involution both sides (rule 21; R12-proven numerically).
// ======================================================================
__global__ __launch_bounds__(256) void gemm_qkv(
    const unsigned short* __restrict__ A,
    const unsigned short* __restrict__ Bt,
    const float* __restrict__ bias,
    unsigned short* __restrict__ qkv,
    unsigned short* __restrict__ vt,
    const float2* __restrict__ cs,
    int M, int K, int T)
{
    const int N = 3072;
    // union: staging As0/As1/Bs0/Bs1 (4 x [128][32]) | vtile [128][136]
    __shared__ __align__(16) unsigned short smem[17408];
    unsigned short* As0 = smem;
    unsigned short* As1 = smem + 4096;
    unsigned short* Bs0 = smem + 8192;
    unsigned short* Bs1 = smem + 12288;

    const int t    = threadIdx.x;
    const int lane = t & 63;
    const int wv   = t >> 6;
    const int wrow = (wv >> 1) * 64;
    const int wcol = (wv & 1) * 64;
    const int m0 = blockIdx.y * 128;
    const int n0 = blockIdx.x * 128;
    const int col  = lane & 15;
    const int quad = lane >> 4;

    const int srow = (wv << 5) + (lane >> 2);     // wv*32 + 0..15
    // chunk-XOR source swizzle: position (lane&3) holds global chunk
    // (lane&3) ^ (srow&3)   [srow&3 == (lane>>2)&3]
    const int scol = (((lane & 3) ^ ((lane >> 2) & 3)) << 3);
    const unsigned short* a00 = A  + (size_t)(m0 + srow) * K + scol;
    const unsigned short* a10 = a00 + (size_t)16 * K;
    const unsigned short* a01 = a00 + 32;
    const unsigned short* a11 = a10 + 32;
    const unsigned short* b00 = Bt + (size_t)(n0 + srow) * K + scol;
    const unsigned short* b10 = b00 + (size_t)16 * K;
    const unsigned short* b01 = b00 + 32;
    const unsigned short* b11 = b10 + 32;
    // LDS dest stays LINEAR (async constraint): position (lane&3)
    const int dcol = (lane & 3) << 3;
    unsigned short* al0 = &As0[srow * 32 + dcol];
    unsigned short* al1 = &As0[(srow + 16) * 32 + dcol];
    unsigned short* al2 = &As1[srow * 32 + dcol];
    unsigned short* al3 = &As1[(srow + 16) * 32 + dcol];
    unsigned short* bl0 = &Bs0[srow * 32 + dcol];
    unsigned short* bl1 = &Bs0[(srow + 16) * 32 + dcol];
    unsigned short* bl2 = &Bs1[srow * 32 + dcol];
    unsigned short* bl3 = &Bs1[(srow + 16) * 32 + dcol];

    f32x4 acc[4][4];
    #pragma unroll
    for (int i = 0; i < 4; ++i)
        #pragma unroll
        for (int j = 0; j < 4; ++j)
            acc[i][j] = (f32x4){0.f, 0.f, 0.f, 0.f};

    // frag-read chunk: global chunk quad lives at position quad^(row&3);
    // row = wrow/wcol + mt*16 + col  ->  row&3 == col&3 (lane-constant)
    const int qoff = ((quad ^ (col & 3)) << 3);

    for (int k0 = 0; k0 < K; k0 += 64) {
        async_lds16(a00, al0);
        async_lds16(a10, al1);
        async_lds16(a01, al2);
        async_lds16(a11, al3);
        async_lds16(b00, bl0);
        async_lds16(b10, bl1);
        async_lds16(b01, bl2);
        async_lds16(b11, bl3);
        a00 += 64; a10 += 64; a01 += 64; a11 += 64;
        b00 += 64; b10 += 64; b01 += 64; b11 += 64;
        __syncthreads();
        short8 af[2][4], bf[2][4];
        #pragma unroll
        for (int mt = 0; mt < 4; ++mt) {
            af[0][mt] = *(const short8*)&As0[(wrow + mt * 16 + col) * 32 + qoff];
            af[1][mt] = *(const short8*)&As1[(wrow + mt * 16 + col) * 32 + qoff];
        }
        #pragma unroll
        for (int nt = 0; nt < 4; ++nt) {
            bf[0][nt] = *(const short8*)&Bs0[(wcol + nt * 16 + col) * 32 + qoff];
            bf[1][nt] = *(const short8*)&Bs1[(wcol + nt * 16 + col) * 32 + qoff];
        }
        #pragma unroll
        for (int ks = 0; ks < 2; ++ks)
            #pragma unroll
            for (int mt = 0; mt < 4; ++mt)
                #pragma unroll
                for (int nt = 0; nt < 4; ++nt)
                    acc[mt][nt] = __builtin_amdgcn_mfma_f32_16x16x32_bf16(
                        af[ks][mt], bf[ks][nt], acc[mt][nt], 0, 0, 0);
        __syncthreads();
    }

    // ---- bias (all paths) ----
    #pragma unroll
    for (int nt = 0; nt < 4; ++nt) {
        const float bv = bias[n0 + wcol + nt * 16 + col];
        #pragma unroll
        for (int mt = 0; mt < 4; ++mt)
            #pragma unroll
            for (int r = 0; r < 4; ++r)
                acc[mt][nt][r] += bv;
    }

    const int b     = m0 / T;          // batch (tile never spans batches)
    const int tpos0 = m0 - b * T;

    if (n0 < 2048) {
        // ---- q/k: RMSNorm + RoPE, store bf16 to qkv ----
        const int n_lin = n0 + wcol;
        const float scale = (n_lin < 1024) ? 0.18033688011112042f : 1.0f; // log2e/8 for q
        #pragma unroll
        for (int mt = 0; mt < 4; ++mt) {
            #pragma unroll
            for (int r = 0; r < 4; ++r) {
                float ss = acc[mt][0][r] * acc[mt][0][r]
                         + acc[mt][1][r] * acc[mt][1][r]
                         + acc[mt][2][r] * acc[mt][2][r]
                         + acc[mt][3][r] * acc[mt][3][r];
                ss += __shfl_xor(ss, 1, 64);
                ss += __shfl_xor(ss, 2, 64);
                ss += __shfl_xor(ss, 4, 64);
                ss += __shfl_xor(ss, 8, 64);
                const float rn = rsqrtf(ss * (1.0f / 64.0f) + EPSV) * scale;
                const int tpos = tpos0 + wrow + mt * 16 + (quad << 2) + r;
                const float2 c0 = cs[tpos * 32 + col];
                const float2 c1 = cs[tpos * 32 + 16 + col];
                const float o0 = (acc[mt][0][r] * c0.x - acc[mt][2][r] * c0.y) * rn;
                const float o1 = (acc[mt][1][r] * c1.x - acc[mt][3][r] * c1.y) * rn;
                const float o2 = (acc[mt][2][r] * c0.x + acc[mt][0][r] * c0.y) * rn;
                const float o3 = (acc[mt][3][r] * c1.x + acc[mt][1][r] * c1.y) * rn;
                const int m = m0 + wrow + mt * 16 + (quad << 2) + r;
                unsigned short* qr = qkv + (size_t)m * N + n_lin + col;
                qr[0]  = f2bf(o0);
                qr[16] = f2bf(o1);
                qr[32] = f2bf(o2);
                qr[48] = f2bf(o3);
            }
        }
    } else {
        // ---- v: transpose via LDS bounce, store to vt[bh*64+d][T] ----
        unsigned short (*vtile)[136] = (unsigned short(*)[136])smem;
        __syncthreads();   // staging buffers dead; safe to repurpose
        #pragma unroll
        for (int nt = 0; nt < 4; ++nt)
            #pragma unroll
            for (int mt = 0; mt < 4; ++mt)
                #pragma unroll
                for (int r = 0; r < 4; ++r)
                    vtile[wcol + nt * 16 + col][wrow + mt * 16 + (quad << 2) + r]
                        = f2bf(acc[mt][nt][r]);
        __syncthreads();
        const int td = t >> 4;          // 0..15
        const int mloc = (t & 15) << 3; // 0,8,..,120
        const int h2base = (n0 - 2048) >> 6;
        #pragma unroll
        for (int i = 0; i < 8; ++i) {
            const int dl = td + i * 16;
            const short8 o = *(const short8*)&vtile[dl][mloc];
            const int h2 = h2base + (dl >> 6);
            const size_t row = ((size_t)(b * 16 + h2) << 6) + (dl & 63);
            *(short8*)&vt[row * T + tpos0 + mloc] = o;
        }
    }
}

// ======================================================================
// bf16 MFMA GEMM, 128(M) x 64(N) (skinny-N gemm2), fp32 out.
// R8 2-phase BK=32 ping-pong + R14 chunk-XOR bank swizzle (same as
// gemm_qkv: source chunk (lane&3)^(row&3), read chunk quad^(col&3)).
// ======================================================================
__global__ __launch_bounds__(256) void gemm_bf16_n64(
    const unsigned short* __restrict__ A,
    const unsigned short* __restrict__ Bt,
    const float* __restrict__ bias,
    float* __restrict__ C,
    int M, int N, int K)
{
    // As[2][128][32]: [0,8192)  Bs[2][64][32]: [8192,12288)  (ushort idx)
    __shared__ __align__(16) unsigned short smem[12288];
    const int t    = threadIdx.x;
    const int lane = t & 63;
    const int wv   = t >> 6;
    const int wrow = wv << 5;
    const int m0 = blockIdx.y * 128;
    const int n0 = blockIdx.x * 64;
    const int col  = lane & 15;
    const int quad = lane >> 4;

    const int srw = lane >> 2;
    // source chunk swizzle (row&3 == srw&3)
    const int sck = (((lane & 3) ^ (srw & 3)) << 3);
    const unsigned short* aP0 = A  + (size_t)(m0 + (wv << 4) + srw) * K + sck;
    const unsigned short* aP1 = aP0 + (size_t)64 * K;
    const unsigned short* bP0 = Bt + (size_t)(n0 + (wv << 4) + srw) * K + sck;
    const int stoff = (wv << 9) + (lane << 3);    // linear dest
    unsigned short* aD = smem + stoff;
    unsigned short* bD = smem + 8192 + stoff;

    f32x4 acc[2][4];
    #pragma unroll
    for (int i = 0; i < 2; ++i)
        #pragma unroll
        for (int j = 0; j < 4; ++j)
            acc[i][j] = (f32x4){0.f, 0.f, 0.f, 0.f};

    // prologue
    async_lds16(aP0, aD);  async_lds16(aP1, aD + 2048);
    async_lds16(bP0, bD);
    aP0 += 32; aP1 += 32; bP0 += 32;

    const int qoff = ((quad ^ (col & 3)) << 3);   // frag-read chunk

    const int NK = K >> 5;
    for (int kt = 0; kt < NK; ++kt) {
        __syncthreads();
        if (kt + 1 < NK) {
            const int nbA = ((kt + 1) & 1) << 12;   // *4096
            const int nbB = ((kt + 1) & 1) << 11;   // *2048
            async_lds16(aP0, aD + nbA);  async_lds16(aP1, aD + nbA + 2048);
            async_lds16(bP0, bD + nbB);
            aP0 += 32; aP1 += 32; bP0 += 32;
        }
        const unsigned short* Ac = smem + ((kt & 1) << 12);
        const unsigned short* Bc = smem + 8192 + ((kt & 1) << 11);
        short8 af[2], bf[4];
        #pragma unroll
        for (int mt = 0; mt < 2; ++mt)
            af[mt] = *(const short8*)&Ac[(wrow + mt * 16 + col) * 32 + qoff];
        #pragma unroll
        for (int nt = 0; nt < 4; ++nt)
            bf[nt] = *(const short8*)&Bc[(nt * 16 + col) * 32 + qoff];
        #pragma unroll
        for (int mt = 0; mt < 2; ++mt)
            #pragma unroll
            for (int nt = 0; nt < 4; ++nt)
                acc[mt][nt] = __builtin_amdgcn_mfma_f32_16x16x32_bf16(
                    af[mt], bf[nt], acc[mt][nt], 0, 0, 0);
    }

    const int rowq = quad << 2;
    #pragma unroll
    for (int nt = 0; nt < 4; ++nt) {
        const int n = n0 + nt * 16 + col;
        const float bv = bias[n];
        #pragma unroll
        for (int mt = 0; mt < 2; ++mt) {
            #pragma unroll
            for (int r = 0; r < 4; ++r) {
                const int m = m0 + wrow + mt * 16 + rowq + r;
                C[(size_t)m * N + n] = acc[mt][nt][r] + bv;
            }
        }
    }
}

// ======================================================================
// MFMA flash attention, FIXED-MAX softmax, q-tile 128, 8 waves x 16 q
// (R4/R5/R7 verified structure).
// ======================================================================
__global__ __launch_bounds__(512, 4) void flash_attn_mfma(
    const unsigned short* __restrict__ qkv,
    const unsigned short* __restrict__ vt,
    unsigned short* __restrict__ yb,
    int B, int T)
{
    const int bh = blockIdx.x;
    const int b  = bh >> 4, h = bh & 15;
    const int ny = (int)gridDim.y;
    const int y  = (int)blockIdx.y;
    const int hny = (ny + 1) >> 1;
    const int jq = (y < hny) ? (ny - 1 - y) : (y - hny);   // balanced pairing
    const int q0 = jq << 7;
    const int t  = threadIdx.x;
    const int lane = t & 63;
    const int w    = t >> 6;       // 0..7, each owns 16 q-rows
    const int col  = lane & 15;
    const int quad = lane >> 4;

    __shared__ __align__(16) unsigned short smem[25600];
    unsigned short* Kb = smem;
    unsigned short* Vb = smem + 8192;
    unsigned short* Ps = smem + 16384;

    const unsigned short* qb  = qkv + (size_t)b * T * 3072 + (h << 6);
    const unsigned short* kb  = qb + 1024;
    const unsigned short* vtb = vt + (size_t)bh * 64 * T;

    const int qw = q0 + (w << 4);        // wave's first q row (16 rows)
    const int qg = qw + col;             // lane's q row

    short8 qf[2];
    {
        const unsigned short* qrow = qb + (size_t)qg * 3072 + (quad << 3);
        qf[0] = *(const short8*)&qrow[0];
        qf[1] = *(const short8*)&qrow[32];
    }

    f32x4 oacc[4];
    #pragma unroll
    for (int i = 0; i < 4; ++i) oacc[i] = (f32x4){0.f, 0.f, 0.f, 0.f};
    float l_i = 0.f;   // per-lane partial; reduced across quads in epilogue

    const int sr = t >> 3;                         // row 0..63
    const int sg = (((t & 7) ^ (sr & 7)) << 3);    // swizzled chunk * 8 elems
    const unsigned short* kp = kb  + (size_t)sr * 3072 + sg;
    const unsigned short* vp = vtb + (size_t)sr * T + sg;

    async_lds16(kp, Kb + (t << 3));
    async_lds16(vp, Vb + (t << 3));
    kp += (size_t)64 * 3072; vp += 64;

    const int cs0 = ((quad ^ (col & 7)) << 3);
    const int cs1 = (((4 + quad) ^ (col & 7)) << 3);

    const int last_kt = (q0 + 127) >> 6;
    int cur = 0;
    for (int kt = 0; kt <= last_kt; ++kt) {
        const int k0 = kt << 6;
        __syncthreads();   // drains async -> buf[cur] ready; prev compute done
        if (kt < last_kt) {
            async_lds16(kp, Kb + ((cur ^ 1) << 12) + (t << 3));
            async_lds16(vp, Vb + ((cur ^ 1) << 12) + (t << 3));
            kp += (size_t)64 * 3072; vp += 64;
        }

        if (k0 <= qw + 15) {
            const unsigned short* Kc = Kb + (cur << 12);
            const unsigned short* Vc = Vb + (cur << 12);

            // ---- S^T = K @ Q^T ----
            f32x4 st[4];
            #pragma unroll
            for (int i = 0; i < 4; ++i) st[i] = (f32x4){0.f, 0.f, 0.f, 0.f};
            __builtin_amdgcn_s_setprio(1);
            #pragma unroll
            for (int ks = 0; ks < 2; ++ks)
                #pragma unroll
                for (int mt = 0; mt < 4; ++mt) {
                    const short8 kf = *(const short8*)&Kc[(mt * 16 + col) * 64 + (ks ? cs1 : cs0)];
                    st[mt] = __builtin_amdgcn_mfma_f32_16x16x32_bf16(kf, qf[ks], st[mt], 0, 0, 0);
                }
            __builtin_amdgcn_s_setprio(0);

            // ---- fixed-max softmax: p = exp2(s), mask via exp2(-inf)=0 ----
            const bool diag = (k0 + 63 > qw);
            unsigned short* pw = Ps + ((w << 4) + col) * 72;
            float rs = 0.f;
            #pragma unroll
            for (int mt = 0; mt < 4; ++mt) {
                float x0 = st[mt][0], x1 = st[mt][1];
                float x2 = st[mt][2], x3 = st[mt][3];
                if (diag) {
                    const int sbase = k0 + mt * 16 + (quad << 2);
                    if (sbase + 0 > qg) x0 = -INFINITY;
                    if (sbase + 1 > qg) x1 = -INFINITY;
                    if (sbase + 2 > qg) x2 = -INFINITY;
                    if (sbase + 3 > qg) x3 = -INFINITY;
                }
                const float p0 = __builtin_amdgcn_exp2f(x0);
                const float p1 = __builtin_amdgcn_exp2f(x1);
                const float p2 = __builtin_amdgcn_exp2f(x2);
                const float p3 = __builtin_amdgcn_exp2f(x3);
                rs += (p0 + p1) + (p2 + p3);
                uint2 pk;
                pk.x = pack_bf16_ru(p0, p1);
                pk.y = pack_bf16_ru(p2, p3);
                *(uint2*)&pw[mt * 16 + (quad << 2)] = pk;
            }
            l_i += rs;

            // ---- O^T += V^T @ P^T ----
            __builtin_amdgcn_s_setprio(1);
            #pragma unroll
            for (int ks = 0; ks < 2; ++ks) {
                const short8 pf = *(const short8*)&Ps[((w << 4) + col) * 72 + ks * 32 + (quad << 3)];
                #pragma unroll
                for (int mt = 0; mt < 4; ++mt) {
                    const short8 vf = *(const short8*)&Vc[(mt * 16 + col) * 64 + (ks ? cs1 : cs0)];
                    oacc[mt] = __builtin_amdgcn_mfma_f32_16x16x32_bf16(vf, pf, oacc[mt], 0, 0, 0);
                }
            }
            __builtin_amdgcn_s_setprio(0);
        }
        cur ^= 1;
    }

    // ---- epilogue: reduce l across quads, normalize, store ----
    l_i += __shfl_xor(l_i, 16, 64);
    l_i += __shfl_xor(l_i, 32, 64);
    const float inv = 1.0f / l_i;
    unsigned short* yrow = yb + (size_t)(b * T + qg) * 1024 + (h << 6);
    #pragma unroll
    for (int mt = 0; mt < 4; ++mt) {
        ushort4 yv;
        yv.x = f2bf(oacc[mt][0] * inv);
        yv.y = f2bf(oacc[mt][1] * inv);
        yv.z = f2bf(oacc[mt][2] * inv);
        yv.w = f2bf(oacc[mt][3] * inv);
        *(ushort4*)&yrow[mt * 16 + (quad << 2)] = yv;
    }
}

// ======================================================================
extern "C" void kernel_launch(void* const* d_in, const int* in_sizes, int n_in,
                              void* d_out, int out_size, void* d_ws, size_t ws_size,
                              hipStream_t stream)
{
    const float* x      = (const float*)d_in[0];
    const float* cosp   = (const float*)d_in[1];
    const float* sinp   = (const float*)d_in[2];
    const float* W_attn = (const float*)d_in[3];
    const float* b_attn = (const float*)d_in[4];
    const float* W_proj = (const float*)d_in[5];
    const float* b_proj = (const float*)d_in[6];
    float* out = (float*)d_out;

    const int C = 1024, H = 16;
    const int T  = in_sizes[1] / 64;     // cos: (T, 64)
    const int BT = in_sizes[0] / C;      // B*T
    const int B  = BT / T;

    // workspace layout (ushort units unless noted)
    float2* csb          = (float2*)d_ws;                       // T*32 float2
    unsigned short* qkvb = (unsigned short*)(csb + (size_t)T * 32); // BT*3072
    unsigned short* xb   = qkvb + (size_t)BT * 3072;            // BT*1024
    unsigned short* Wab  = xb   + (size_t)BT * 1024;            // 3072*1024
    unsigned short* Wpb  = Wab  + (size_t)3072 * 1024;          // 1024*1024
    unsigned short* yb   = Wpb  + (size_t)1024 * 1024;          // BT*1024
    unsigned short* vtb  = yb   + (size_t)BT * 1024;            // BT*1024

    const int castBlocks = BT * C / 1024;
    const int csBlocks   = T * 32 / 256;
    prep_cast_transpose<<<dim3(castBlocks + 4096 + csBlocks), dim3(256), 0, stream>>>(
        x, xb, BT * C, W_attn, Wab, W_proj, Wpb, cosp, sinp, csb, castBlocks);

    gemm_qkv<<<dim3(3 * C / 128, BT / 128), dim3(256), 0, stream>>>(
        xb, Wab, b_attn, qkvb, vtb, csb, BT, C, T);

    flash_attn_mfma<<<dim3(B * H, T / 128), dim3(512), 0, stream>>>(
        qkvb, vtb, yb, B, T);

    gemm_bf16_n64<<<dim3(C / 64, BT / 128), dim3(256), 0, stream>>>(
        yb, Wpb, b_proj, out, BT, C, C);
}

// Round 15
// 173.692 us; speedup vs baseline: 1.0139x; 1.0139x over previous
//
#include <hip/hip_runtime.h>
#include <math.h>

#define EPSV 1.1920929e-07f

typedef __attribute__((ext_vector_type(8))) short short8;
typedef __attribute__((ext_vector_type(4))) float f32x4;

__device__ __forceinline__ float bf2f(unsigned short u) {
    union { unsigned int i; float f; } c; c.i = ((unsigned int)u) << 16; return c.f;
}
__device__ __forceinline__ unsigned short f2bf(float f) {
    union { float f; unsigned int i; } c; c.f = f;
    unsigned int r = c.i + 0x7FFFu + ((c.i >> 16) & 1u);   // RNE
    return (unsigned short)(r >> 16);
}
// pack two f32 -> two bf16 (round-half-up) in one u32: low=a, high=b
__device__ __forceinline__ unsigned int pack_bf16_ru(float a, float b) {
    union { float f; unsigned int i; } ca, cb; ca.f = a; cb.f = b;
    return __builtin_amdgcn_perm(cb.i + 0x8000u, ca.i + 0x8000u, 0x07060302u);
}
// async global -> LDS, 16 B per lane (dest = wave-uniform base + lane*16)
__device__ __forceinline__ void async_lds16(const unsigned short* g, unsigned short* l) {
    __builtin_amdgcn_global_load_lds(
        (const __attribute__((address_space(1))) unsigned int*)g,
        (__attribute__((address_space(3))) unsigned int*)l, 16, 0, 0);
}

// ======================================================================
// MERGED prep: fp32->bf16 cast of x | transpose+cast of both weights |
// packed cos/sin table cs[T][32] (float2; cos[d]=cos[d%32] by concat).
// ======================================================================
__global__ __launch_bounds__(256) void prep_cast_transpose(
    const float* __restrict__ x, unsigned short* __restrict__ xb, int nCast,
    const float* __restrict__ Wa, unsigned short* __restrict__ Wat,
    const float* __restrict__ Wp, unsigned short* __restrict__ Wpt,
    const float* __restrict__ cosp, const float* __restrict__ sinp,
    float2* __restrict__ cs, int castBlocks)
{
    __shared__ float tile[32][33];
    const int bxg = blockIdx.x;
    if (bxg < castBlocks) {
        const int i = (bxg * 256 + threadIdx.x) * 4;
        if (i >= nCast) return;
        const float4 v = *(const float4*)&x[i];
        ushort4 o;
        o.x = f2bf(v.x); o.y = f2bf(v.y); o.z = f2bf(v.z); o.w = f2bf(v.w);
        *(ushort4*)&xb[i] = o;
        return;
    }
    if (bxg >= castBlocks + 4096) {   // cs table part
        const int i = (bxg - castBlocks - 4096) * 256 + threadIdx.x;
        const int tp = i >> 5, dp = i & 31;
        cs[i] = make_float2(cosp[tp * 64 + dp], sinp[tp * 64 + dp]);
        return;
    }
    const int r0 = bxg - castBlocks;
    int bx = r0 & 127;                      // 0..127
    const int by = r0 >> 7;                 // 0..31
    const float* W; unsigned short* Wt; int N;
    if (bx < 96) { W = Wa; Wt = Wat; N = 3072; }
    else         { W = Wp; Wt = Wpt; N = 1024; bx -= 96; }
    const int n0 = bx * 32, k0 = by * 32;
    const int r = threadIdx.x >> 3, c4 = (threadIdx.x & 7) * 4;
    const float4 v = *(const float4*)&W[(size_t)(k0 + r) * N + n0 + c4];
    tile[r][c4 + 0] = v.x; tile[r][c4 + 1] = v.y;
    tile[r][c4 + 2] = v.z; tile[r][c4 + 3] = v.w;
    __syncthreads();
    ushort4 o;
    o.x = f2bf(tile[c4 + 0][r]); o.y = f2bf(tile[c4 + 1][r]);
    o.z = f2bf(tile[c4 + 2][r]); o.w = f2bf(tile[c4 + 3][r]);
    *(ushort4*)&Wt[(size_t)(n0 + r) * 1024 + k0 + c4] = o;
}

// ======================================================================
// FUSED qkv GEMM (N=3072) with fused RMSNorm+RoPE / V-transpose epilogue.
// R13 structure (1-phase BK=64) + R14 chunk-XOR bank swizzle (verified:
// all dispatches dropped below the 41.8 us poison fills, from 48.8).
// ======================================================================
__global__ __launch_bounds__(256) void gemm_qkv(
    const unsigned short* __restrict__ A,
    const unsigned short* __restrict__ Bt,
    const float* __restrict__ bias,
    unsigned short* __restrict__ qkv,
    unsigned short* __restrict__ vt,
    const float2* __restrict__ cs,
    int M, int K, int T)
{
    const int N = 3072;
    // union: staging As0/As1/Bs0/Bs1 (4 x [128][32]) | vtile [128][136]
    __shared__ __align__(16) unsigned short smem[17408];
    unsigned short* As0 = smem;
    unsigned short* As1 = smem + 4096;
    unsigned short* Bs0 = smem + 8192;
    unsigned short* Bs1 = smem + 12288;

    const int t    = threadIdx.x;
    const int lane = t & 63;
    const int wv   = t >> 6;
    const int wrow = (wv >> 1) * 64;
    const int wcol = (wv & 1) * 64;
    const int m0 = blockIdx.y * 128;
    const int n0 = blockIdx.x * 128;
    const int col  = lane & 15;
    const int quad = lane >> 4;

    const int srow = (wv << 5) + (lane >> 2);     // wv*32 + 0..15
    // chunk-XOR source swizzle: position (lane&3) holds global chunk
    // (lane&3) ^ (srow&3)   [srow&3 == (lane>>2)&3]
    const int scol = (((lane & 3) ^ ((lane >> 2) & 3)) << 3);
    const unsigned short* a00 = A  + (size_t)(m0 + srow) * K + scol;
    const unsigned short* a10 = a00 + (size_t)16 * K;
    const unsigned short* a01 = a00 + 32;
    const unsigned short* a11 = a10 + 32;
    const unsigned short* b00 = Bt + (size_t)(n0 + srow) * K + scol;
    const unsigned short* b10 = b00 + (size_t)16 * K;
    const unsigned short* b01 = b00 + 32;
    const unsigned short* b11 = b10 + 32;
    // LDS dest stays LINEAR (async constraint): position (lane&3)
    const int dcol = (lane & 3) << 3;
    unsigned short* al0 = &As0[srow * 32 + dcol];
    unsigned short* al1 = &As0[(srow + 16) * 32 + dcol];
    unsigned short* al2 = &As1[srow * 32 + dcol];
    unsigned short* al3 = &As1[(srow + 16) * 32 + dcol];
    unsigned short* bl0 = &Bs0[srow * 32 + dcol];
    unsigned short* bl1 = &Bs0[(srow + 16) * 32 + dcol];
    unsigned short* bl2 = &Bs1[srow * 32 + dcol];
    unsigned short* bl3 = &Bs1[(srow + 16) * 32 + dcol];

    f32x4 acc[4][4];
    #pragma unroll
    for (int i = 0; i < 4; ++i)
        #pragma unroll
        for (int j = 0; j < 4; ++j)
            acc[i][j] = (f32x4){0.f, 0.f, 0.f, 0.f};

    // frag-read chunk: global chunk quad lives at position quad^(row&3);
    // row = wrow/wcol + mt*16 + col  ->  row&3 == col&3 (lane-constant)
    const int qoff = ((quad ^ (col & 3)) << 3);

    for (int k0 = 0; k0 < K; k0 += 64) {
        async_lds16(a00, al0);
        async_lds16(a10, al1);
        async_lds16(a01, al2);
        async_lds16(a11, al3);
        async_lds16(b00, bl0);
        async_lds16(b10, bl1);
        async_lds16(b01, bl2);
        async_lds16(b11, bl3);
        a00 += 64; a10 += 64; a01 += 64; a11 += 64;
        b00 += 64; b10 += 64; b01 += 64; b11 += 64;
        __syncthreads();
        short8 af[2][4], bf[2][4];
        #pragma unroll
        for (int mt = 0; mt < 4; ++mt) {
            af[0][mt] = *(const short8*)&As0[(wrow + mt * 16 + col) * 32 + qoff];
            af[1][mt] = *(const short8*)&As1[(wrow + mt * 16 + col) * 32 + qoff];
        }
        #pragma unroll
        for (int nt = 0; nt < 4; ++nt) {
            bf[0][nt] = *(const short8*)&Bs0[(wcol + nt * 16 + col) * 32 + qoff];
            bf[1][nt] = *(const short8*)&Bs1[(wcol + nt * 16 + col) * 32 + qoff];
        }
        #pragma unroll
        for (int ks = 0; ks < 2; ++ks)
            #pragma unroll
            for (int mt = 0; mt < 4; ++mt)
                #pragma unroll
                for (int nt = 0; nt < 4; ++nt)
                    acc[mt][nt] = __builtin_amdgcn_mfma_f32_16x16x32_bf16(
                        af[ks][mt], bf[ks][nt], acc[mt][nt], 0, 0, 0);
        __syncthreads();
    }

    // ---- bias (all paths) ----
    #pragma unroll
    for (int nt = 0; nt < 4; ++nt) {
        const float bv = bias[n0 + wcol + nt * 16 + col];
        #pragma unroll
        for (int mt = 0; mt < 4; ++mt)
            #pragma unroll
            for (int r = 0; r < 4; ++r)
                acc[mt][nt][r] += bv;
    }

    const int b     = m0 / T;          // batch (tile never spans batches)
    const int tpos0 = m0 - b * T;

    if (n0 < 2048) {
        // ---- q/k: RMSNorm + RoPE, store bf16 to qkv ----
        const int n_lin = n0 + wcol;
        const float scale = (n_lin < 1024) ? 0.18033688011112042f : 1.0f; // log2e/8 for q
        #pragma unroll
        for (int mt = 0; mt < 4; ++mt) {
            #pragma unroll
            for (int r = 0; r < 4; ++r) {
                float ss = acc[mt][0][r] * acc[mt][0][r]
                         + acc[mt][1][r] * acc[mt][1][r]
                         + acc[mt][2][r] * acc[mt][2][r]
                         + acc[mt][3][r] * acc[mt][3][r];
                ss += __shfl_xor(ss, 1, 64);
                ss += __shfl_xor(ss, 2, 64);
                ss += __shfl_xor(ss, 4, 64);
                ss += __shfl_xor(ss, 8, 64);
                const float rn = rsqrtf(ss * (1.0f / 64.0f) + EPSV) * scale;
                const int tpos = tpos0 + wrow + mt * 16 + (quad << 2) + r;
                const float2 c0 = cs[tpos * 32 + col];
                const float2 c1 = cs[tpos * 32 + 16 + col];
                const float o0 = (acc[mt][0][r] * c0.x - acc[mt][2][r] * c0.y) * rn;
                const float o1 = (acc[mt][1][r] * c1.x - acc[mt][3][r] * c1.y) * rn;
                const float o2 = (acc[mt][2][r] * c0.x + acc[mt][0][r] * c0.y) * rn;
                const float o3 = (acc[mt][3][r] * c1.x + acc[mt][1][r] * c1.y) * rn;
                const int m = m0 + wrow + mt * 16 + (quad << 2) + r;
                unsigned short* qr = qkv + (size_t)m * N + n_lin + col;
                qr[0]  = f2bf(o0);
                qr[16] = f2bf(o1);
                qr[32] = f2bf(o2);
                qr[48] = f2bf(o3);
            }
        }
    } else {
        // ---- v: transpose via LDS bounce, store to vt[bh*64+d][T] ----
        unsigned short (*vtile)[136] = (unsigned short(*)[136])smem;
        __syncthreads();   // staging buffers dead; safe to repurpose
        #pragma unroll
        for (int nt = 0; nt < 4; ++nt)
            #pragma unroll
            for (int mt = 0; mt < 4; ++mt)
                #pragma unroll
                for (int r = 0; r < 4; ++r)
                    vtile[wcol + nt * 16 + col][wrow + mt * 16 + (quad << 2) + r]
                        = f2bf(acc[mt][nt][r]);
        __syncthreads();
        const int td = t >> 4;          // 0..15
        const int mloc = (t & 15) << 3; // 0,8,..,120
        const int h2base = (n0 - 2048) >> 6;
        #pragma unroll
        for (int i = 0; i < 8; ++i) {
            const int dl = td + i * 16;
            const short8 o = *(const short8*)&vtile[dl][mloc];
            const int h2 = h2base + (dl >> 6);
            const size_t row = ((size_t)(b * 16 + h2) << 6) + (dl & 63);
            *(short8*)&vt[row * T + tpos0 + mloc] = o;
        }
    }
}

// ======================================================================
// bf16 MFMA GEMM, 128(M) x 64(N) (skinny-N gemm2), fp32 out.
// R8 2-phase BK=32 ping-pong + R14 chunk-XOR bank swizzle.
// ======================================================================
__global__ __launch_bounds__(256) void gemm_bf16_n64(
    const unsigned short* __restrict__ A,
    const unsigned short* __restrict__ Bt,
    const float* __restrict__ bias,
    float* __restrict__ C,
    int M, int N, int K)
{
    // As[2][128][32]: [0,8192)  Bs[2][64][32]: [8192,12288)  (ushort idx)
    __shared__ __align__(16) unsigned short smem[12288];
    const int t    = threadIdx.x;
    const int lane = t & 63;
    const int wv   = t >> 6;
    const int wrow = wv << 5;
    const int m0 = blockIdx.y * 128;
    const int n0 = blockIdx.x * 64;
    const int col  = lane & 15;
    const int quad = lane >> 4;

    const int srw = lane >> 2;
    // source chunk swizzle (row&3 == srw&3)
    const int sck = (((lane & 3) ^ (srw & 3)) << 3);
    const unsigned short* aP0 = A  + (size_t)(m0 + (wv << 4) + srw) * K + sck;
    const unsigned short* aP1 = aP0 + (size_t)64 * K;
    const unsigned short* bP0 = Bt + (size_t)(n0 + (wv << 4) + srw) * K + sck;
    const int stoff = (wv << 9) + (lane << 3);    // linear dest
    unsigned short* aD = smem + stoff;
    unsigned short* bD = smem + 8192 + stoff;

    f32x4 acc[2][4];
    #pragma unroll
    for (int i = 0; i < 2; ++i)
        #pragma unroll
        for (int j = 0; j < 4; ++j)
            acc[i][j] = (f32x4){0.f, 0.f, 0.f, 0.f};

    // prologue
    async_lds16(aP0, aD);  async_lds16(aP1, aD + 2048);
    async_lds16(bP0, bD);
    aP0 += 32; aP1 += 32; bP0 += 32;

    const int qoff = ((quad ^ (col & 3)) << 3);   // frag-read chunk

    const int NK = K >> 5;
    for (int kt = 0; kt < NK; ++kt) {
        __syncthreads();
        if (kt + 1 < NK) {
            const int nbA = ((kt + 1) & 1) << 12;   // *4096
            const int nbB = ((kt + 1) & 1) << 11;   // *2048
            async_lds16(aP0, aD + nbA);  async_lds16(aP1, aD + nbA + 2048);
            async_lds16(bP0, bD + nbB);
            aP0 += 32; aP1 += 32; bP0 += 32;
        }
        const unsigned short* Ac = smem + ((kt & 1) << 12);
        const unsigned short* Bc = smem + 8192 + ((kt & 1) << 11);
        short8 af[2], bf[4];
        #pragma unroll
        for (int mt = 0; mt < 2; ++mt)
            af[mt] = *(const short8*)&Ac[(wrow + mt * 16 + col) * 32 + qoff];
        #pragma unroll
        for (int nt = 0; nt < 4; ++nt)
            bf[nt] = *(const short8*)&Bc[(nt * 16 + col) * 32 + qoff];
        #pragma unroll
        for (int mt = 0; mt < 2; ++mt)
            #pragma unroll
            for (int nt = 0; nt < 4; ++nt)
                acc[mt][nt] = __builtin_amdgcn_mfma_f32_16x16x32_bf16(
                    af[mt], bf[nt], acc[mt][nt], 0, 0, 0);
    }

    const int rowq = quad << 2;
    #pragma unroll
    for (int nt = 0; nt < 4; ++nt) {
        const int n = n0 + nt * 16 + col;
        const float bv = bias[n];
        #pragma unroll
        for (int mt = 0; mt < 2; ++mt) {
            #pragma unroll
            for (int r = 0; r < 4; ++r) {
                const int m = m0 + wrow + mt * 16 + rowq + r;
                C[(size_t)m * N + n] = acc[mt][nt][r] + bv;
            }
        }
    }
}

// ======================================================================
// MFMA flash attention, FIXED-MAX softmax, q-tile 128, 8 waves x 16 q
// (R4/R5/R7 verified structure).
// ======================================================================
__global__ __launch_bounds__(512, 4) void flash_attn_mfma(
    const unsigned short* __restrict__ qkv,
    const unsigned short* __restrict__ vt,
    unsigned short* __restrict__ yb,
    int B, int T)
{
    const int bh = blockIdx.x;
    const int b  = bh >> 4, h = bh & 15;
    const int ny = (int)gridDim.y;
    const int y  = (int)blockIdx.y;
    const int hny = (ny + 1) >> 1;
    const int jq = (y < hny) ? (ny - 1 - y) : (y - hny);   // balanced pairing
    const int q0 = jq << 7;
    const int t  = threadIdx.x;
    const int lane = t & 63;
    const int w    = t >> 6;       // 0..7, each owns 16 q-rows
    const int col  = lane & 15;
    const int quad = lane >> 4;

    __shared__ __align__(16) unsigned short smem[25600];
    unsigned short* Kb = smem;
    unsigned short* Vb = smem + 8192;
    unsigned short* Ps = smem + 16384;

    const unsigned short* qb  = qkv + (size_t)b * T * 3072 + (h << 6);
    const unsigned short* kb  = qb + 1024;
    const unsigned short* vtb = vt + (size_t)bh * 64 * T;

    const int qw = q0 + (w << 4);        // wave's first q row (16 rows)
    const int qg = qw + col;             // lane's q row

    short8 qf[2];
    {
        const unsigned short* qrow = qb + (size_t)qg * 3072 + (quad << 3);
        qf[0] = *(const short8*)&qrow[0];
        qf[1] = *(const short8*)&qrow[32];
    }

    f32x4 oacc[4];
    #pragma unroll
    for (int i = 0; i < 4; ++i) oacc[i] = (f32x4){0.f, 0.f, 0.f, 0.f};
    float l_i = 0.f;   // per-lane partial; reduced across quads in epilogue

    const int sr = t >> 3;                         // row 0..63
    const int sg = (((t & 7) ^ (sr & 7)) << 3);    // swizzled chunk * 8 elems
    const unsigned short* kp = kb  + (size_t)sr * 3072 + sg;
    const unsigned short* vp = vtb + (size_t)sr * T + sg;

    async_lds16(kp, Kb + (t << 3));
    async_lds16(vp, Vb + (t << 3));
    kp += (size_t)64 * 3072; vp += 64;

    const int cs0 = ((quad ^ (col & 7)) << 3);
    const int cs1 = (((4 + quad) ^ (col & 7)) << 3);

    const int last_kt = (q0 + 127) >> 6;
    int cur = 0;
    for (int kt = 0; kt <= last_kt; ++kt) {
        const int k0 = kt << 6;
        __syncthreads();   // drains async -> buf[cur] ready; prev compute done
        if (kt < last_kt) {
            async_lds16(kp, Kb + ((cur ^ 1) << 12) + (t << 3));
            async_lds16(vp, Vb + ((cur ^ 1) << 12) + (t << 3));
            kp += (size_t)64 * 3072; vp += 64;
        }

        if (k0 <= qw + 15) {
            const unsigned short* Kc = Kb + (cur << 12);
            const unsigned short* Vc = Vb + (cur << 12);

            // ---- S^T = K @ Q^T ----
            f32x4 st[4];
            #pragma unroll
            for (int i = 0; i < 4; ++i) st[i] = (f32x4){0.f, 0.f, 0.f, 0.f};
            __builtin_amdgcn_s_setprio(1);
            #pragma unroll
            for (int ks = 0; ks < 2; ++ks)
                #pragma unroll
                for (int mt = 0; mt < 4; ++mt) {
                    const short8 kf = *(const short8*)&Kc[(mt * 16 + col) * 64 + (ks ? cs1 : cs0)];
                    st[mt] = __builtin_amdgcn_mfma_f32_16x16x32_bf16(kf, qf[ks], st[mt], 0, 0, 0);
                }
            __builtin_amdgcn_s_setprio(0);

            // ---- fixed-max softmax: p = exp2(s), mask via exp2(-inf)=0 ----
            const bool diag = (k0 + 63 > qw);
            unsigned short* pw = Ps + ((w << 4) + col) * 72;
            float rs = 0.f;
            #pragma unroll
            for (int mt = 0; mt < 4; ++mt) {
                float x0 = st[mt][0], x1 = st[mt][1];
                float x2 = st[mt][2], x3 = st[mt][3];
                if (diag) {
                    const int sbase = k0 + mt * 16 + (quad << 2);
                    if (sbase + 0 > qg) x0 = -INFINITY;
                    if (sbase + 1 > qg) x1 = -INFINITY;
                    if (sbase + 2 > qg) x2 = -INFINITY;
                    if (sbase + 3 > qg) x3 = -INFINITY;
                }
                const float p0 = __builtin_amdgcn_exp2f(x0);
                const float p1 = __builtin_amdgcn_exp2f(x1);
                const float p2 = __builtin_amdgcn_exp2f(x2);
                const float p3 = __builtin_amdgcn_exp2f(x3);
                rs += (p0 + p1) + (p2 + p3);
                uint2 pk;
                pk.x = pack_bf16_ru(p0, p1);
                pk.y = pack_bf16_ru(p2, p3);
                *(uint2*)&pw[mt * 16 + (quad << 2)] = pk;
            }
            l_i += rs;

            // ---- O^T += V^T @ P^T ----
            __builtin_amdgcn_s_setprio(1);
            #pragma unroll
            for (int ks = 0; ks < 2; ++ks) {
                const short8 pf = *(const short8*)&Ps[((w << 4) + col) * 72 + ks * 32 + (quad << 3)];
                #pragma unroll
                for (int mt = 0; mt < 4; ++mt) {
                    const short8 vf = *(const short8*)&Vc[(mt * 16 + col) * 64 + (ks ? cs1 : cs0)];
                    oacc[mt] = __builtin_amdgcn_mfma_f32_16x16x32_bf16(vf, pf, oacc[mt], 0, 0, 0);
                }
            }
            __builtin_amdgcn_s_setprio(0);
        }
        cur ^= 1;
    }

    // ---- epilogue: reduce l across quads, normalize, store ----
    l_i += __shfl_xor(l_i, 16, 64);
    l_i += __shfl_xor(l_i, 32, 64);
    const float inv = 1.0f / l_i;
    unsigned short* yrow = yb + (size_t)(b * T + qg) * 1024 + (h << 6);
    #pragma unroll
    for (int mt = 0; mt < 4; ++mt) {
        ushort4 yv;
        yv.x = f2bf(oacc[mt][0] * inv);
        yv.y = f2bf(oacc[mt][1] * inv);
        yv.z = f2bf(oacc[mt][2] * inv);
        yv.w = f2bf(oacc[mt][3] * inv);
        *(ushort4*)&yrow[mt * 16 + (quad << 2)] = yv;
    }
}

// ======================================================================
extern "C" void kernel_launch(void* const* d_in, const int* in_sizes, int n_in,
                              void* d_out, int out_size, void* d_ws, size_t ws_size,
                              hipStream_t stream)
{
    const float* x      = (const float*)d_in[0];
    const float* cosp   = (const float*)d_in[1];
    const float* sinp   = (const float*)d_in[2];
    const float* W_attn = (const float*)d_in[3];
    const float* b_attn = (const float*)d_in[4];
    const float* W_proj = (const float*)d_in[5];
    const float* b_proj = (const float*)d_in[6];
    float* out = (float*)d_out;

    const int C = 1024, H = 16;
    const int T  = in_sizes[1] / 64;     // cos: (T, 64)
    const int BT = in_sizes[0] / C;      // B*T
    const int B  = BT / T;

    // workspace layout (ushort units unless noted)
    float2* csb          = (float2*)d_ws;                       // T*32 float2
    unsigned short* qkvb = (unsigned short*)(csb + (size_t)T * 32); // BT*3072
    unsigned short* xb   = qkvb + (size_t)BT * 3072;            // BT*1024
    unsigned short* Wab  = xb   + (size_t)BT * 1024;            // 3072*1024
    unsigned short* Wpb  = Wab  + (size_t)3072 * 1024;          // 1024*1024
    unsigned short* yb   = Wpb  + (size_t)1024 * 1024;          // BT*1024
    unsigned short* vtb  = yb   + (size_t)BT * 1024;            // BT*1024

    const int castBlocks = BT * C / 1024;
    const int csBlocks   = T * 32 / 256;
    prep_cast_transpose<<<dim3(castBlocks + 4096 + csBlocks), dim3(256), 0, stream>>>(
        x, xb, BT * C, W_attn, Wab, W_proj, Wpb, cosp, sinp, csb, castBlocks);

    gemm_qkv<<<dim3(3 * C / 128, BT / 128), dim3(256), 0, stream>>>(
        xb, Wab, b_attn, qkvb, vtb, csb, BT, C, T);

    flash_attn_mfma<<<dim3(B * H, T / 128), dim3(512), 0, stream>>>(
        qkvb, vtb, yb, B, T);

    gemm_bf16_n64<<<dim3(C / 64, BT / 128), dim3(256), 0, stream>>>(
        yb, Wpb, b_proj, out, BT, C, C);
}